// Round 6
// baseline (885.073 us; speedup 1.0000x reference)
//
#include <hip/hip_runtime.h>

namespace {

constexpr int T_LEN = 2048;
constexpr int B_TOT = 2048;
constexpr int H1 = 36;
constexpr int NB = 16;      // batches per block = MFMA N
constexpr int BLOCK = 640;  // 9 A-waves (M-tiles) + 1 L2/x-feeder wave
constexpr int RS = 72;      // h row stride in halves (144B, 16B-aligned)

typedef _Float16 f16x8 __attribute__((ext_vector_type(8)));
typedef _Float16 h16x2 __attribute__((ext_vector_type(2)));
typedef float f32x4 __attribute__((ext_vector_type(4)));

__device__ __forceinline__ float fdot2(float wb, float hb, float acc) {
#if __has_builtin(__builtin_amdgcn_fdot2)
  return __builtin_amdgcn_fdot2(__builtin_bit_cast(h16x2, wb),
                                __builtin_bit_cast(h16x2, hb), acc, false);
#else
  float d;
  asm("v_dot2_f32_f16 %0, %1, %2, %3" : "=v"(d) : "v"(wb), "v"(hb), "0"(acc));
  return d;
#endif
}
__device__ __forceinline__ float pack2h(float a, float b) {
  h16x2 t = {(_Float16)a, (_Float16)b};
  return __builtin_bit_cast(float, t);
}
// Quad-broadcast via DPP quad_perm (VALU pipe, off LDS).
template <int CTRL>
__device__ __forceinline__ float qb(float v) {
  return __builtin_bit_cast(
      float, __builtin_amdgcn_update_dpp(0, __builtin_bit_cast(int, v), CTRL,
                                         0xf, 0xf, true));
}
// Packed f16 relu on a dword (2 halves): lets the L2 wave relu raw h itself
// so A-waves write ONE b16 per step (no separate relu plane).
__device__ __forceinline__ float pkrelu(float v) {
  float r;
  asm("v_pk_max_f16 %0, %1, %2" : "=v"(r) : "v"(v), "v"(0.f));
  return r;
}
__device__ __forceinline__ float fexp2(float x) { return __builtin_amdgcn_exp2f(x); }
__device__ __forceinline__ float frcp(float x) { return __builtin_amdgcn_rcpf(x); }

// Scaled-gate LSTM cell, 8-trans form: pre-activations arrive pre-multiplied
// by -log2e (i,f,o) / -2log2e (g); cS tracks -2log2e*c.
__device__ __forceinline__ float lstm_unit(float pi, float pf, float pg, float po,
                                           float& cS) {
  const float Ei = fexp2(pi);
  const float Ef = fexp2(pf);
  const float Eg = fexp2(pg);
  const float Eo = fexp2(po);
  const float F = frcp(1.f + Ef);
  const float Rig = frcp((1.f + Ei) * (1.f + Eg));
  const float numg = fmaf(Eg, 2.88539008f, -2.88539008f);  // -2log2e*(1-Eg)
  cS = fmaf(F, cS, numg * Rig);
  const float Ec = fexp2(cS);
  const float Roc = frcp((1.f + Eo) * (1.f + Ec));
  return (1.f - Ec) * Roc;  // O * tanh(c)
}

// Raw barrier: producer-side lgkmcnt(0) only (no vmcnt/expcnt drain).
__device__ __forceinline__ void step_sync() {
  asm volatile("s_waitcnt lgkmcnt(0)" ::: "memory");
  __builtin_amdgcn_s_barrier();
  __builtin_amdgcn_sched_barrier(0);
  asm volatile("" ::: "memory");
}

__global__ __launch_bounds__(BLOCK) void lstm2_kernel(
    const float* __restrict__ x, const float* __restrict__ Wih1,
    const float* __restrict__ Whh1, const float* __restrict__ bih1,
    const float* __restrict__ bhh1, const float* __restrict__ Wih2,
    const float* __restrict__ Whh2, const float* __restrict__ bih2,
    const float* __restrict__ bhh2, float* __restrict__ out)
{
  // lds[buf][batch][k]: raw h (f16) + B1-stuffing:
  //   k=36: x_hi, 37: x_lo, 38,39: 1.0 (bias cols); 40..71 stay zero forever.
  __shared__ __align__(16) _Float16 lds[2][NB][RS];

  const int tid = threadIdx.x;
  const int wid = tid >> 6;
  const int lane = tid & 63;
  const int m = lane & 15;   // A-row group / B,C: batch col
  const int q = lane >> 4;   // k-group / C row-group
  const int g0 = blockIdx.x * NB;
  const bool isA = wid < 9;

  for (int i = tid; i < 2 * NB * RS; i += BLOCK)
    ((_Float16*)lds)[i] = (_Float16)0.f;
  __syncthreads();
  if (tid < NB) {  // bias columns (both bufs) + x_0 into buf1
    lds[0][tid][38] = (_Float16)1.f;
    lds[0][tid][39] = (_Float16)1.f;
    lds[1][tid][38] = (_Float16)1.f;
    lds[1][tid][39] = (_Float16)1.f;
    const float x0 = x[(size_t)(g0 + tid) * T_LEN];
    const _Float16 xh0 = (_Float16)x0;
    lds[1][tid][36] = xh0;
    lds[1][tid][37] = (_Float16)(x0 - (float)xh0);
  }
  __syncthreads();

  // ---- A-wave setup: tile wid = units wid*4..+3, all 4 gates, 16 batches.
  // Weights pre-scaled by the gate's -log2e / -2log2e factor.
  // A1 (k=32..39, q==0 lanes only): [Whh tail 32..35 | Wih | Wih | b_hi | b_lo]
  f16x8 A0 = {}, A1 = {};
  float c1 = 0.f;
  int ku = 0;
  if (isA) {
    const int u0 = wid * 4;
    ku = u0 + q;  // this lane's unit (C rows 4q+r = unit u0+q, gate r)
    const float sga = ((m & 3) == 2) ? -2.88539008f : -1.44269504f;
    const int ra = (m & 3) * H1 + (u0 + (m >> 2));
#pragma unroll
    for (int j = 0; j < 8; ++j)
      A0[j] = (_Float16)(sga * Whh1[ra * H1 + q * 8 + j]);  // k=q*8+j < 32
#pragma unroll
    for (int j = 0; j < 8; ++j) A1[j] = (_Float16)0.f;
    if (q == 0) {
#pragma unroll
      for (int j = 0; j < 4; ++j)
        A1[j] = (_Float16)(sga * Whh1[ra * H1 + 32 + j]);  // tail k=32..35
      const _Float16 wih = (_Float16)(sga * Wih1[ra]);
      A1[4] = wih;  // * x_hi
      A1[5] = wih;  // * x_lo  -> (x_hi+x_lo)*wih = x*wih
      const float bb = sga * (bih1[ra] + bhh1[ra]);
      const _Float16 bh = (_Float16)bb;
      A1[6] = bh;                           // * 1.0
      A1[7] = (_Float16)(bb - (float)bh);   // * 1.0 (bias residual)
    }
  }

  // ---- L2 wave (wid==9): lane = batch*4 + gate; ALSO the x-feeder.
  //      (x-feed moved here from wave 8 so all 9 A-waves are identical ->
  //       minimal barrier-arrival skew on the critical A-chain.)
  const int lb = lane >> 2, lg = lane & 3;
  float w2[18];
  float whg = 0.f, b2 = 0.f, c2S = 0.f, h2 = 0.f;
  float* outp = nullptr;
  const float* xc = nullptr;
  float4 qx = make_float4(0.f, 0.f, 0.f, 0.f);
#pragma unroll
  for (int k = 0; k < 18; ++k) w2[k] = 0.f;
  if (wid == 9) {
    const float s2 = (lg == 2) ? -2.88539008f : -1.44269504f;
    const float* wr = Wih2 + lg * H1;
#pragma unroll
    for (int k = 0; k < 18; ++k)
      w2[k] = pack2h(s2 * wr[2 * k], s2 * wr[2 * k + 1]);
    whg = s2 * Whh2[lg];
    b2 = s2 * (bih2[lg] + bhh2[lg]);
    outp = out + (size_t)(g0 + lb) * T_LEN;
    xc = x + (size_t)(g0 + lb) * T_LEN;
    qx = *(const float4*)xc;  // x[0..3] (4-way dup across the quad, harmless)
  }

  float4 ov = make_float4(0.f, 0.f, 0.f, 0.f);
  const f32x4 z4 = {0.f, 0.f, 0.f, 0.f};

  // Round i: A-waves compute h_i from buf[ib] (h_{i-1}, x_i); L2 wave writes
  // x_{i+1} into buf[wb] and computes out[i-1]. One raw barrier per round.
  auto step = [&](int i, int s, float xw) {
    const int ib = (s + 1) & 1;
    const int wb = s & 1;
    if (isA) {
      const f16x8 B0 = *(const f16x8*)&lds[ib][m][q * 8];  // k=q*8..+7, 64 lanes
      f16x8 B1;
#pragma unroll
      for (int j = 0; j < 8; ++j) B1[j] = (_Float16)0.f;
      if (q == 0)  // exec-masked 16-lane read: k=32..39 only exists for q==0
        B1 = *(const f16x8*)&lds[ib][m][32];
      const f32x4 cc1 = __builtin_amdgcn_mfma_f32_16x16x32_f16(A0, B0, z4, 0, 0, 0);
      const f32x4 cc2 = __builtin_amdgcn_mfma_f32_16x16x32_f16(A1, B1, z4, 0, 0, 0);
      const float h = lstm_unit(cc1[0] + cc2[0], cc1[1] + cc2[1],
                                cc1[2] + cc2[2], cc1[3] + cc2[3], c1);
      lds[wb][m][ku] = (_Float16)h;  // single b16 write (no relu plane)
    } else {
      // x-feed for next round (cheap, lands early, off the A critical path)
      if (lg == 0) {
        const _Float16 xh = (_Float16)xw;
        h16x2 xp = {xh, (_Float16)(xw - (float)xh)};
        *(h16x2*)&lds[wb][lb][36] = xp;
      }
      if (i > 0) {
        const char* rp = (const char*)&lds[ib][lb][0];  // raw h_{i-1}, row lb
        const float4 r0 = *(const float4*)rp;
        const float4 r1 = *(const float4*)(rp + 16);
        const float4 r2 = *(const float4*)(rp + 32);
        const float4 r3 = *(const float4*)(rp + 48);
        const float2 r4 = *(const float2*)(rp + 64);   // k=32..35 only
        const float f[18] = {
            pkrelu(r0.x), pkrelu(r0.y), pkrelu(r0.z), pkrelu(r0.w),
            pkrelu(r1.x), pkrelu(r1.y), pkrelu(r1.z), pkrelu(r1.w),
            pkrelu(r2.x), pkrelu(r2.y), pkrelu(r2.z), pkrelu(r2.w),
            pkrelu(r3.x), pkrelu(r3.y), pkrelu(r3.z), pkrelu(r3.w),
            pkrelu(r4.x), pkrelu(r4.y)};
        // 4 accumulators: dot dep-chain depth 5; seed with h2/bias term.
        float a0 = fdot2(w2[0], f[0], fmaf(h2, whg, b2));
        float a1 = fdot2(w2[1], f[1], 0.f);
        float a2 = fdot2(w2[2], f[2], 0.f);
        float a3 = fdot2(w2[3], f[3], 0.f);
#pragma unroll
        for (int k = 4; k < 16; k += 4) {
          a0 = fdot2(w2[k], f[k], a0);
          a1 = fdot2(w2[k + 1], f[k + 1], a1);
          a2 = fdot2(w2[k + 2], f[k + 2], a2);
          a3 = fdot2(w2[k + 3], f[k + 3], a3);
        }
        a0 = fdot2(w2[16], f[16], a0);
        a1 = fdot2(w2[17], f[17], a1);
        const float pre = (a0 + a2) + (a1 + a3);  // scaled gate lg pre-act
        const float pI = qb<0x00>(pre);
        const float pF = qb<0x55>(pre);
        const float pG = qb<0xAA>(pre);
        const float pO = qb<0xFF>(pre);
        h2 = lstm_unit(pI, pF, pG, pO, c2S);  // = out[i-1], replicated in quad
        if (s == 1) ov.x = h2;
        else if (s == 2) ov.y = h2;
        else if (s == 3) ov.z = h2;
        else {
          ov.w = h2;
          if (lg == 0) *(float4*)(outp + (i - 4)) = ov;  // out[i-4..i-1]
        }
      }
    }
    step_sync();
  };

  for (int i0 = 0; i0 < T_LEN; i0 += 4) {
    float4 qn = qx;
    if (wid == 9) {  // prefetch next x quad (clamped at tail)
      const int tn = (i0 + 4 < T_LEN) ? (i0 + 4) : (T_LEN - 4);
      qn = *(const float4*)(xc + tn);
    }
    step(i0 + 0, 0, qx.y);  // write x[i0+1]
    step(i0 + 1, 1, qx.z);  // write x[i0+2]
    step(i0 + 2, 2, qx.w);  // write x[i0+3]
    step(i0 + 3, 3, qn.x);  // write x[i0+4]
    qx = qn;
  }
  // Final round: A computes discarded h_2048; L2 emits out[2047] and stores
  // out[2044..2047].
  step(T_LEN, 0, qx.y);
}

}  // namespace

extern "C" void kernel_launch(void* const* d_in, const int* in_sizes, int n_in,
                              void* d_out, int out_size, void* d_ws, size_t ws_size,
                              hipStream_t stream) {
  const float* x    = (const float*)d_in[0];
  const float* Wih1 = (const float*)d_in[1];
  const float* Whh1 = (const float*)d_in[2];
  const float* bih1 = (const float*)d_in[3];
  const float* bhh1 = (const float*)d_in[4];
  const float* Wih2 = (const float*)d_in[5];
  const float* Whh2 = (const float*)d_in[6];
  const float* bih2 = (const float*)d_in[7];
  const float* bhh2 = (const float*)d_in[8];
  float* out = (float*)d_out;

  dim3 grid(B_TOT / NB);  // 128 blocks x 16 batches
  dim3 block(BLOCK);      // 9 MFMA waves + 1 L2/x-feeder wave
  hipLaunchKernelGGL(lstm2_kernel, grid, block, 0, stream,
                     x, Wih1, Whh1, bih1, bhh1, Wih2, Whh2, bih2, bhh2, out);
}

// Round 7
// 868.838 us; speedup vs baseline: 1.0187x; 1.0187x over previous
//
#include <hip/hip_runtime.h>

namespace {

constexpr int T_LEN = 2048;
constexpr int B_TOT = 2048;
constexpr int H1 = 36;
constexpr int NB = 16;      // batches per block = MFMA N
constexpr int BLOCK = 640;  // 9 A-waves (M-tiles) + 1 L2/x-feeder wave
constexpr int RS = 72;      // h row stride in halves (144B, 16B-aligned)

typedef _Float16 f16x8 __attribute__((ext_vector_type(8)));
typedef _Float16 h16x2 __attribute__((ext_vector_type(2)));
typedef float f32x4 __attribute__((ext_vector_type(4)));

__device__ __forceinline__ float fdot2(float wb, float hb, float acc) {
#if __has_builtin(__builtin_amdgcn_fdot2)
  return __builtin_amdgcn_fdot2(__builtin_bit_cast(h16x2, wb),
                                __builtin_bit_cast(h16x2, hb), acc, false);
#else
  float d;
  asm("v_dot2_f32_f16 %0, %1, %2, %3" : "=v"(d) : "v"(wb), "v"(hb), "0"(acc));
  return d;
#endif
}
__device__ __forceinline__ float pack2h(float a, float b) {
  h16x2 t = {(_Float16)a, (_Float16)b};
  return __builtin_bit_cast(float, t);
}
// Quad-broadcast via DPP quad_perm (VALU pipe, off LDS).
template <int CTRL>
__device__ __forceinline__ float qb(float v) {
  return __builtin_bit_cast(
      float, __builtin_amdgcn_update_dpp(0, __builtin_bit_cast(int, v), CTRL,
                                         0xf, 0xf, true));
}
// Packed f16 relu on a dword (2 halves). Runs in the L2 wave (which now has a
// full round of slack), so A-waves write ONE raw-h b16/step (no relu plane).
__device__ __forceinline__ float pkrelu(float v) {
  float r;
  asm("v_pk_max_f16 %0, %1, %2" : "=v"(r) : "v"(v), "v"(0.f));
  return r;
}
__device__ __forceinline__ float fexp2(float x) { return __builtin_amdgcn_exp2f(x); }
__device__ __forceinline__ float frcp(float x) { return __builtin_amdgcn_rcpf(x); }

// Scaled-gate LSTM cell, 8-trans form: pre-activations arrive pre-multiplied
// by -log2e (i,f,o) / -2log2e (g); cS tracks -2log2e*c.
__device__ __forceinline__ float lstm_unit(float pi, float pf, float pg, float po,
                                           float& cS) {
  const float Ei = fexp2(pi);
  const float Ef = fexp2(pf);
  const float Eg = fexp2(pg);
  const float Eo = fexp2(po);
  const float F = frcp(1.f + Ef);
  const float Rig = frcp((1.f + Ei) * (1.f + Eg));
  const float numg = fmaf(Eg, 2.88539008f, -2.88539008f);  // -2log2e*(1-Eg)
  cS = fmaf(F, cS, numg * Rig);
  const float Ec = fexp2(cS);
  const float Roc = frcp((1.f + Eo) * (1.f + Ec));
  return (1.f - Ec) * Roc;  // O * tanh(c)
}

// Raw barrier: producer-side lgkmcnt(0) only (no vmcnt/expcnt drain).
__device__ __forceinline__ void step_sync() {
  asm volatile("s_waitcnt lgkmcnt(0)" ::: "memory");
  __builtin_amdgcn_s_barrier();
  __builtin_amdgcn_sched_barrier(0);
  asm volatile("" ::: "memory");
}

__global__ __launch_bounds__(BLOCK) void lstm2_kernel(
    const float* __restrict__ x, const float* __restrict__ Wih1,
    const float* __restrict__ Whh1, const float* __restrict__ bih1,
    const float* __restrict__ bhh1, const float* __restrict__ Wih2,
    const float* __restrict__ Whh2, const float* __restrict__ bih2,
    const float* __restrict__ bhh2, float* __restrict__ out)
{
  // FOUR rotating buffers (period matches the 4-step unroll). Round i:
  //   A reads  buf[(i-1)&3]  (h_{i-1} + x_i + bias cols)
  //   A writes buf[ i   &3]  (h_i);  L2 writes x_{i+1} there too (k=36,37)
  //   L2 reads buf[(i-2)&3]  (h_{i-2}) -> L2 chain gets a FULL ROUND of slack
  // All three indices are distinct mod 4 -> no read/write overlap in a round.
  // k layout per row: 0..35 h, 36 x_hi, 37 x_lo, 38,39 = 1.0 (bias), 40.. = 0.
  __shared__ __align__(16) _Float16 lds[4][NB][RS];

  const int tid = threadIdx.x;
  const int wid = tid >> 6;
  const int lane = tid & 63;
  const int m = lane & 15;   // A-row group / B,C: batch col
  const int q = lane >> 4;   // k-group / C row-group
  const int g0 = blockIdx.x * NB;
  const bool isA = wid < 9;

  for (int i = tid; i < 4 * NB * RS; i += BLOCK)
    ((_Float16*)lds)[i] = (_Float16)0.f;
  __syncthreads();
  if (tid < NB) {  // bias columns in all 4 bufs + x_0 into buf3 (read by round 0)
#pragma unroll
    for (int b = 0; b < 4; ++b) {
      lds[b][tid][38] = (_Float16)1.f;
      lds[b][tid][39] = (_Float16)1.f;
    }
    const float x0 = x[(size_t)(g0 + tid) * T_LEN];
    const _Float16 xh0 = (_Float16)x0;
    lds[3][tid][36] = xh0;
    lds[3][tid][37] = (_Float16)(x0 - (float)xh0);
  }
  __syncthreads();

  // ---- A-wave setup: tile wid = units wid*4..+3, all 4 gates, 16 batches.
  // Weights pre-scaled by the gate's -log2e / -2log2e factor.
  // A1 (k=32..39, q==0 lanes only): [Whh tail 32..35 | Wih | Wih | b_hi | b_lo]
  f16x8 A0 = {}, A1 = {};
  float c1 = 0.f;
  int ku = 0;
  if (isA) {
    const int u0 = wid * 4;
    ku = u0 + q;  // this lane's unit (C rows 4q+r = unit u0+q, gate r)
    const float sga = ((m & 3) == 2) ? -2.88539008f : -1.44269504f;
    const int ra = (m & 3) * H1 + (u0 + (m >> 2));
#pragma unroll
    for (int j = 0; j < 8; ++j)
      A0[j] = (_Float16)(sga * Whh1[ra * H1 + q * 8 + j]);  // k=q*8+j < 32
#pragma unroll
    for (int j = 0; j < 8; ++j) A1[j] = (_Float16)0.f;
    if (q == 0) {
#pragma unroll
      for (int j = 0; j < 4; ++j)
        A1[j] = (_Float16)(sga * Whh1[ra * H1 + 32 + j]);  // tail k=32..35
      const _Float16 wih = (_Float16)(sga * Wih1[ra]);
      A1[4] = wih;  // * x_hi
      A1[5] = wih;  // * x_lo  -> (x_hi+x_lo)*wih = x*wih
      const float bb = sga * (bih1[ra] + bhh1[ra]);
      const _Float16 bh = (_Float16)bb;
      A1[6] = bh;                           // * 1.0
      A1[7] = (_Float16)(bb - (float)bh);   // * 1.0 (bias residual)
    }
  }

  // ---- L2 wave (wid==9): lane = batch*4 + gate; also the x-feeder.
  const int lb = lane >> 2, lg = lane & 3;
  float w2[18];
  float whg = 0.f, b2 = 0.f, c2S = 0.f, h2 = 0.f;
  float* outp = nullptr;
  const float* xc = nullptr;
  float4 qx = make_float4(0.f, 0.f, 0.f, 0.f);
#pragma unroll
  for (int k = 0; k < 18; ++k) w2[k] = 0.f;
  if (wid == 9) {
    const float s2 = (lg == 2) ? -2.88539008f : -1.44269504f;
    const float* wr = Wih2 + lg * H1;
#pragma unroll
    for (int k = 0; k < 18; ++k)
      w2[k] = pack2h(s2 * wr[2 * k], s2 * wr[2 * k + 1]);
    whg = s2 * Whh2[lg];
    b2 = s2 * (bih2[lg] + bhh2[lg]);
    outp = out + (size_t)(g0 + lb) * T_LEN;
    xc = x + (size_t)(g0 + lb) * T_LEN;
    qx = *(const float4*)xc;  // x[0..3] (4-way dup across the quad, harmless)
  }

  float4 ov = make_float4(0.f, 0.f, 0.f, 0.f);
  const f32x4 z4 = {0.f, 0.f, 0.f, 0.f};

  // Round i (s = i&3): A computes h_i; L2 feeds x_{i+1} and computes out[i-2]
  // (2-step-deep pipeline -> L2 chain never gates the barrier).
  auto step = [&](int i, int s, bool doA, float xw) {
    const int rb = (s + 3) & 3;  // A reads h_{i-1}, x_i
    const int wb = s;            // A writes h_i; L2 writes x_{i+1}
    const int lr = (s + 2) & 3;  // L2 reads h_{i-2}
    if (isA) {
      if (doA) {
        const f16x8 B0 = *(const f16x8*)&lds[rb][m][q * 8];       // k=q*8..+7
        const f16x8 B1 = *(const f16x8*)&lds[rb][m][32 + q * 8];  // zeros pad
        const f32x4 cc1 = __builtin_amdgcn_mfma_f32_16x16x32_f16(A0, B0, z4, 0, 0, 0);
        const f32x4 cc2 = __builtin_amdgcn_mfma_f32_16x16x32_f16(A1, B1, z4, 0, 0, 0);
        const float h = lstm_unit(cc1[0] + cc2[0], cc1[1] + cc2[1],
                                  cc1[2] + cc2[2], cc1[3] + cc2[3], c1);
        lds[wb][m][ku] = (_Float16)h;  // single raw-h b16 write
      }
    } else {
      if (doA && lg == 0) {  // x_{i+1} for round i+1 (slack-side work)
        const _Float16 xh = (_Float16)xw;
        h16x2 xp = {xh, (_Float16)(xw - (float)xh)};
        *(h16x2*)&lds[wb][lb][36] = xp;
      }
      if (i > 1) {
        const char* rp = (const char*)&lds[lr][lb][0];  // raw h_{i-2}, row lb
        const float4 r0 = *(const float4*)rp;
        const float4 r1 = *(const float4*)(rp + 16);
        const float4 r2 = *(const float4*)(rp + 32);
        const float4 r3 = *(const float4*)(rp + 48);
        const float2 r4 = *(const float2*)(rp + 64);   // k=32..35
        const float f[18] = {
            pkrelu(r0.x), pkrelu(r0.y), pkrelu(r0.z), pkrelu(r0.w),
            pkrelu(r1.x), pkrelu(r1.y), pkrelu(r1.z), pkrelu(r1.w),
            pkrelu(r2.x), pkrelu(r2.y), pkrelu(r2.z), pkrelu(r2.w),
            pkrelu(r3.x), pkrelu(r3.y), pkrelu(r3.z), pkrelu(r3.w),
            pkrelu(r4.x), pkrelu(r4.y)};
        // 4 accumulators: dot dep-chain depth 5; seed with h2/bias term.
        float a0 = fdot2(w2[0], f[0], fmaf(h2, whg, b2));
        float a1 = fdot2(w2[1], f[1], 0.f);
        float a2 = fdot2(w2[2], f[2], 0.f);
        float a3 = fdot2(w2[3], f[3], 0.f);
#pragma unroll
        for (int k = 4; k < 16; k += 4) {
          a0 = fdot2(w2[k], f[k], a0);
          a1 = fdot2(w2[k + 1], f[k + 1], a1);
          a2 = fdot2(w2[k + 2], f[k + 2], a2);
          a3 = fdot2(w2[k + 3], f[k + 3], a3);
        }
        a0 = fdot2(w2[16], f[16], a0);
        a1 = fdot2(w2[17], f[17], a1);
        const float pre = (a0 + a2) + (a1 + a3);  // scaled gate lg pre-act
        const float pI = qb<0x00>(pre);
        const float pF = qb<0x55>(pre);
        const float pG = qb<0xAA>(pre);
        const float pO = qb<0xFF>(pre);
        h2 = lstm_unit(pI, pF, pG, pO, c2S);  // = out[i-2], replicated in quad
        // slot = (i-2)&3 = (s+2)&3
        if (s == 2) ov.x = h2;
        else if (s == 3) ov.y = h2;
        else if (s == 0) ov.z = h2;
        else {
          ov.w = h2;
          if (lg == 0 && i >= 5) *(float4*)(outp + (i - 5)) = ov;  // out[i-5..i-2]
        }
      }
    }
    step_sync();
  };

  for (int i0 = 0; i0 < T_LEN; i0 += 4) {
    float4 qn = qx;
    if (wid == 9) {  // prefetch next x quad (clamped at tail)
      const int tn = (i0 + 4 < T_LEN) ? (i0 + 4) : (T_LEN - 4);
      qn = *(const float4*)(xc + tn);
    }
    step(i0 + 0, 0, true, qx.y);  // write x[i0+1]
    step(i0 + 1, 1, true, qx.z);  // write x[i0+2]
    step(i0 + 2, 2, true, qx.w);  // write x[i0+3]
    step(i0 + 3, 3, true, qn.x);  // write x[i0+4]
    qx = qn;
  }
  // Drain: 2 rounds, A idle; L2 emits out[2046], then out[2047] + final store.
  step(T_LEN + 0, 0, false, 0.f);
  step(T_LEN + 1, 1, false, 0.f);
}

}  // namespace

extern "C" void kernel_launch(void* const* d_in, const int* in_sizes, int n_in,
                              void* d_out, int out_size, void* d_ws, size_t ws_size,
                              hipStream_t stream) {
  const float* x    = (const float*)d_in[0];
  const float* Wih1 = (const float*)d_in[1];
  const float* Whh1 = (const float*)d_in[2];
  const float* bih1 = (const float*)d_in[3];
  const float* bhh1 = (const float*)d_in[4];
  const float* Wih2 = (const float*)d_in[5];
  const float* Whh2 = (const float*)d_in[6];
  const float* bih2 = (const float*)d_in[7];
  const float* bhh2 = (const float*)d_in[8];
  float* out = (float*)d_out;

  dim3 grid(B_TOT / NB);  // 128 blocks x 16 batches
  dim3 block(BLOCK);      // 9 MFMA waves + 1 L2/x-feeder wave
  hipLaunchKernelGGL(lstm2_kernel, grid, block, 0, stream,
                     x, Wih1, Whh1, bih1, bhh1, Wih2, Whh2, bih2, bhh2, out);
}

// Round 8
// 758.939 us; speedup vs baseline: 1.1662x; 1.1448x over previous
//
#include <hip/hip_runtime.h>

namespace {

constexpr int T_LEN = 2048;
constexpr int B_TOT = 2048;
constexpr int H1 = 36;
constexpr int NB = 16;      // batches per block = MFMA N
constexpr int BLOCK = 640;  // 9 A-waves + 1 L2-MFMA/x-feeder wave
constexpr int RS = 72;      // row stride in halves (144B, 16B-aligned)

typedef _Float16 f16x8 __attribute__((ext_vector_type(8)));
typedef _Float16 h16x2 __attribute__((ext_vector_type(2)));
typedef float f32x4 __attribute__((ext_vector_type(4)));

__device__ __forceinline__ float fexp2(float x) { return __builtin_amdgcn_exp2f(x); }
__device__ __forceinline__ float frcp(float x) { return __builtin_amdgcn_rcpf(x); }

// Scaled-gate LSTM cell, 8-trans form: pre-activations arrive pre-multiplied
// by -log2e (i,f,o) / -2log2e (g); cS tracks -2log2e*c.
__device__ __forceinline__ float lstm_unit(float pi, float pf, float pg, float po,
                                           float& cS) {
  const float Ei = fexp2(pi);
  const float Ef = fexp2(pf);
  const float Eg = fexp2(pg);
  const float Eo = fexp2(po);
  const float F = frcp(1.f + Ef);
  const float Rig = frcp((1.f + Ei) * (1.f + Eg));
  const float numg = fmaf(Eg, 2.88539008f, -2.88539008f);  // -2log2e*(1-Eg)
  cS = fmaf(F, cS, numg * Rig);
  const float Ec = fexp2(cS);
  const float Roc = frcp((1.f + Eo) * (1.f + Ec));
  return (1.f - Ec) * Roc;  // O * tanh(c)
}

// Raw barrier: producer-side lgkmcnt(0) only (no vmcnt/expcnt drain).
__device__ __forceinline__ void step_sync() {
  asm volatile("s_waitcnt lgkmcnt(0)" ::: "memory");
  __builtin_amdgcn_s_barrier();
  __builtin_amdgcn_sched_barrier(0);
  asm volatile("" ::: "memory");
}

__global__ __launch_bounds__(BLOCK) void lstm2_kernel(
    const float* __restrict__ x, const float* __restrict__ Wih1,
    const float* __restrict__ Whh1, const float* __restrict__ bih1,
    const float* __restrict__ bhh1, const float* __restrict__ Wih2,
    const float* __restrict__ Whh2, const float* __restrict__ bih2,
    const float* __restrict__ bhh2, float* __restrict__ out)
{
  // lds[buf][plane][batch][k]:
  //  plane0 (raw):  k=0..35 h, 36 x_hi, 37 x_lo, 38,39 = 1.0 (bias), 40.. = 0
  //  plane1 (relu): k=0..35 relu(h),    36,37 = 0,  38,39 = 1.0,      40.. = 0
  // A-waves read plane0; the L2-MFMA wave reads plane1 (x cols zero there, and
  // its A1 x-columns are zero too).
  __shared__ __align__(16) _Float16 lds[2][2][NB][RS];

  const int tid = threadIdx.x;
  const int wid = tid >> 6;
  const int lane = tid & 63;
  const int m = lane & 15;   // A-row / B,C: batch col
  const int q = lane >> 4;   // k-group / C row-group
  const int g0 = blockIdx.x * NB;
  const bool isA = wid < 9;

  for (int i = tid; i < 2 * 2 * NB * RS; i += BLOCK)
    ((_Float16*)lds)[i] = (_Float16)0.f;
  __syncthreads();
  if (tid < NB) {  // bias columns (both bufs, both planes) + x_0 into buf1
    lds[0][0][tid][38] = (_Float16)1.f; lds[0][0][tid][39] = (_Float16)1.f;
    lds[1][0][tid][38] = (_Float16)1.f; lds[1][0][tid][39] = (_Float16)1.f;
    lds[0][1][tid][38] = (_Float16)1.f; lds[0][1][tid][39] = (_Float16)1.f;
    lds[1][1][tid][38] = (_Float16)1.f; lds[1][1][tid][39] = (_Float16)1.f;
    const float x0 = x[(size_t)(g0 + tid) * T_LEN];
    const _Float16 xh0 = (_Float16)x0;
    lds[1][0][tid][36] = xh0;
    lds[1][0][tid][37] = (_Float16)(x0 - (float)xh0);
  }
  __syncthreads();

  // ---- Operand setup (A0/A1 shared by both wave kinds) ----
  f16x8 A0 = {}, A1 = {};
  float c1 = 0.f;   // A-wave cell state
  int ku = 0;
  if (isA) {
    const int u0 = wid * 4;
    ku = u0 + q;  // this lane's unit (C rows 4q+r = unit u0+q, gate r)
    const float sga = ((m & 3) == 2) ? -2.88539008f : -1.44269504f;
    const int ra = (m & 3) * H1 + (u0 + (m >> 2));
#pragma unroll
    for (int j = 0; j < 8; ++j)
      A0[j] = (_Float16)(sga * Whh1[ra * H1 + q * 8 + j]);  // k=q*8+j < 32
    if (q == 0) {
#pragma unroll
      for (int j = 0; j < 4; ++j)
        A1[j] = (_Float16)(sga * Whh1[ra * H1 + 32 + j]);  // tail k=32..35
      const _Float16 wih = (_Float16)(sga * Wih1[ra]);
      A1[4] = wih;  // * x_hi
      A1[5] = wih;  // * x_lo
      const float bb = sga * (bih1[ra] + bhh1[ra]);
      const _Float16 bh = (_Float16)bb;
      A1[6] = bh;                           // * 1.0
      A1[7] = (_Float16)(bb - (float)bh);   // * 1.0 (bias residual)
    }
  } else {
    // L2-MFMA wave: A row m = gate m for m<4 (pre-scaled), rows 4..15 zero.
    // Lane (q=0, m) then receives all 4 gate pre-acts for batch m in cc[0..3].
    if (m < 4) {
      const float s2 = (m == 2) ? -2.88539008f : -1.44269504f;
      const float* wr = Wih2 + m * H1;
#pragma unroll
      for (int j = 0; j < 8; ++j)
        A0[j] = (_Float16)(s2 * wr[q * 8 + j]);
      if (q == 0) {
#pragma unroll
        for (int j = 0; j < 4; ++j)
          A1[j] = (_Float16)(s2 * wr[32 + j]);  // tail k=32..35
        // A1[4],A1[5] stay 0 (x columns absent in layer 2)
        const float bb = s2 * (bih2[m] + bhh2[m]);
        const _Float16 bh = (_Float16)bb;
        A1[6] = bh;
        A1[7] = (_Float16)(bb - (float)bh);
      }
    }
  }

  // ---- Precomputed LDS read pointers (loop-invariant; no per-round addr ALU).
  // B1 broadcast trick: q!=0 lanes' B1 is structurally zero -> all 48 point at
  // ONE shared zero 16B region (same-address -> LDS broadcast, ~free service).
  const _Float16* zr = &lds[0][1][0][40];  // never written, stays zero
  const int pl = isA ? 0 : 1;              // A reads raw, L2 reads relu
  const _Float16* b0p0 = &lds[0][pl][m][q * 8];
  const _Float16* b0p1 = &lds[1][pl][m][q * 8];
  const _Float16* b1p0 = (q == 0) ? &lds[0][pl][m][32] : zr;
  const _Float16* b1p1 = (q == 0) ? &lds[1][pl][m][32] : zr;

  // ---- L2 wave extras: per-gate recurrent weights, x-feeder state ----
  float whg4[4] = {0.f, 0.f, 0.f, 0.f};
  float c2S = 0.f, h2 = 0.f;
  float* outp = nullptr;
  const float* xc = nullptr;
  float4 qx = make_float4(0.f, 0.f, 0.f, 0.f);
  if (wid == 9) {
#pragma unroll
    for (int r = 0; r < 4; ++r)
      whg4[r] = ((r == 2) ? -2.88539008f : -1.44269504f) * Whh2[r];
    outp = out + (size_t)(g0 + m) * T_LEN;
    xc = x + (size_t)(g0 + m) * T_LEN;
    if (lane < 16) qx = *(const float4*)xc;  // x[0..3]
  }

  float4 ov = make_float4(0.f, 0.f, 0.f, 0.f);
  const f32x4 z4 = {0.f, 0.f, 0.f, 0.f};

  // Round i: A-waves compute h_i from buf[ib] (h_{i-1}, x_i) and write h_i /
  // relu(h_i) into buf[wb]; L2 wave feeds x_{i+1} into buf[wb] and computes
  // out[i-1] from buf[ib]'s relu plane. One raw barrier per round.
  auto step = [&](int i, int s, float xw) {
    const int ib = (s + 1) & 1;
    const int wb = s & 1;
    if (wid == 9 && lane < 16) {  // x_{i+1} feed (shortest stream carries it)
      const _Float16 xh = (_Float16)xw;
      h16x2 xp = {xh, (_Float16)(xw - (float)xh)};
      *(h16x2*)&lds[wb][0][lane][36] = xp;
    }
    if (isA || i > 0) {
      const f16x8 B0 = *(const f16x8*)(ib ? b0p1 : b0p0);
      const f16x8 B1 = *(const f16x8*)(ib ? b1p1 : b1p0);
      const f32x4 cc1 = __builtin_amdgcn_mfma_f32_16x16x32_f16(A0, B0, z4, 0, 0, 0);
      const f32x4 cc2 = __builtin_amdgcn_mfma_f32_16x16x32_f16(A1, B1, z4, 0, 0, 0);
      if (isA) {
        const float h = lstm_unit(cc1[0] + cc2[0], cc1[1] + cc2[1],
                                  cc1[2] + cc2[2], cc1[3] + cc2[3], c1);
        const _Float16 hh = (_Float16)h;
        lds[wb][0][m][ku] = hh;
        lds[wb][1][m][ku] = (hh > (_Float16)0.f) ? hh : (_Float16)0.f;
      } else {
        // lane (q=0, m): cc[r] = s2(r)*(W2_r . relu(h_{i-1}) + b2_r); add the
        // lane-local recurrent term and activate. q!=0 lanes compute bounded
        // garbage (zero A rows) that is never read or stored.
        float pre[4];
#pragma unroll
        for (int r = 0; r < 4; ++r)
          pre[r] = fmaf(whg4[r], h2, cc1[r] + cc2[r]);
        h2 = lstm_unit(pre[0], pre[1], pre[2], pre[3], c2S);  // = out[i-1]
        if (s == 1) ov.x = h2;
        else if (s == 2) ov.y = h2;
        else if (s == 3) ov.z = h2;
        else {
          ov.w = h2;
          if (lane < 16) *(float4*)(outp + (i - 4)) = ov;  // out[i-4..i-1]
        }
      }
    }
    step_sync();
  };

  for (int i0 = 0; i0 < T_LEN; i0 += 4) {
    float4 qn = qx;
    if (wid == 9 && lane < 16) {  // prefetch next x quad (clamped at tail)
      const int tn = (i0 + 4 < T_LEN) ? (i0 + 4) : (T_LEN - 4);
      qn = *(const float4*)(xc + tn);
    }
    step(i0 + 0, 0, qx.y);  // write x[i0+1]
    step(i0 + 1, 1, qx.z);  // write x[i0+2]
    step(i0 + 2, 2, qx.w);  // write x[i0+3]
    step(i0 + 3, 3, qn.x);  // write x[i0+4]
    qx = qn;
  }
  // Final round: A computes discarded h_2048; L2 emits out[2047] and stores
  // out[2044..2047].
  step(T_LEN, 0, qx.y);
}

}  // namespace

extern "C" void kernel_launch(void* const* d_in, const int* in_sizes, int n_in,
                              void* d_out, int out_size, void* d_ws, size_t ws_size,
                              hipStream_t stream) {
  const float* x    = (const float*)d_in[0];
  const float* Wih1 = (const float*)d_in[1];
  const float* Whh1 = (const float*)d_in[2];
  const float* bih1 = (const float*)d_in[3];
  const float* bhh1 = (const float*)d_in[4];
  const float* Wih2 = (const float*)d_in[5];
  const float* Whh2 = (const float*)d_in[6];
  const float* bih2 = (const float*)d_in[7];
  const float* bhh2 = (const float*)d_in[8];
  float* out = (float*)d_out;

  dim3 grid(B_TOT / NB);  // 128 blocks x 16 batches
  dim3 block(BLOCK);      // 9 A-waves + 1 L2-MFMA/x-feeder wave
  hipLaunchKernelGGL(lstm2_kernel, grid, block, 0, stream,
                     x, Wih1, Whh1, bih1, bhh1, Wih2, Whh2, bih2, bhh2, out);
}

// Round 11
// 748.523 us; speedup vs baseline: 1.1824x; 1.0139x over previous
//
#include <hip/hip_runtime.h>

namespace {

constexpr int T_LEN = 2048;
constexpr int B_TOT = 2048;
constexpr int H1 = 36;
constexpr int NB = 16;      // batches per block = MFMA N
constexpr int BLOCK = 640;  // 9 A-waves + 1 L2-MFMA/x-feeder wave
constexpr int RS = 72;      // row stride in halves (144B, 16B-aligned)

typedef _Float16 f16x8 __attribute__((ext_vector_type(8)));
typedef _Float16 h16x2 __attribute__((ext_vector_type(2)));
typedef float f32x4 __attribute__((ext_vector_type(4)));

__device__ __forceinline__ float fexp2(float x) { return __builtin_amdgcn_exp2f(x); }
__device__ __forceinline__ float frcp(float x) { return __builtin_amdgcn_rcpf(x); }

// Scaled-gate LSTM cell, 8-trans form (R8-verified): pre-activations arrive
// pre-multiplied by -log2e (i,f,o) / -2log2e (g); cS tracks -2log2e*c.
__device__ __forceinline__ float lstm_unit(float pi, float pf, float pg, float po,
                                           float& cS) {
  const float Ei = fexp2(pi);
  const float Ef = fexp2(pf);
  const float Eg = fexp2(pg);
  const float Eo = fexp2(po);
  const float F = frcp(1.f + Ef);
  const float Rig = frcp((1.f + Ei) * (1.f + Eg));
  const float numg = fmaf(Eg, 2.88539008f, -2.88539008f);  // -2log2e*(1-Eg)
  cS = fmaf(F, cS, numg * Rig);
  const float Ec = fexp2(cS);
  const float Roc = frcp((1.f + Eo) * (1.f + Ec));
  return (1.f - Ec) * Roc;  // O * tanh(c)
}

// Raw barrier: producer-side lgkmcnt(0) only (no vmcnt/expcnt drain).
__device__ __forceinline__ void step_sync() {
  asm volatile("s_waitcnt lgkmcnt(0)" ::: "memory");
  __builtin_amdgcn_s_barrier();
  __builtin_amdgcn_sched_barrier(0);
  asm volatile("" ::: "memory");
}

__global__ __launch_bounds__(BLOCK) void lstm2_kernel(
    const float* __restrict__ x, const float* __restrict__ Wih1,
    const float* __restrict__ Whh1, const float* __restrict__ bih1,
    const float* __restrict__ bhh1, const float* __restrict__ Wih2,
    const float* __restrict__ Whh2, const float* __restrict__ bih2,
    const float* __restrict__ bhh2, float* __restrict__ out)
{
  // lds[buf][plane][batch][k]:
  //  plane0 (raw):  k=0..35 h, 36 x_hi, 37 x_lo, 38,39 = 1.0 (bias), 40.. = 0
  //  plane1 (relu): k=0..35 relu(h),    36,37 = 0,  38,39 = 1.0,      40.. = 0
  __shared__ __align__(16) _Float16 lds[2][2][NB][RS];

  const int tid = threadIdx.x;
  const int wid = tid >> 6;
  const int lane = tid & 63;
  const int m = lane & 15;   // A-row / B,C: batch col
  const int q = lane >> 4;   // k-group / C row-group
  const int g0 = blockIdx.x * NB;
  const bool isA = wid < 9;

  for (int i = tid; i < 2 * 2 * NB * RS; i += BLOCK)
    ((_Float16*)lds)[i] = (_Float16)0.f;
  __syncthreads();
  if (tid < NB) {  // bias columns (both bufs, both planes) + x_0 into buf1
    lds[0][0][tid][38] = (_Float16)1.f; lds[0][0][tid][39] = (_Float16)1.f;
    lds[1][0][tid][38] = (_Float16)1.f; lds[1][0][tid][39] = (_Float16)1.f;
    lds[0][1][tid][38] = (_Float16)1.f; lds[0][1][tid][39] = (_Float16)1.f;
    lds[1][1][tid][38] = (_Float16)1.f; lds[1][1][tid][39] = (_Float16)1.f;
    const float x0 = x[(size_t)(g0 + tid) * T_LEN];
    const _Float16 xh0 = (_Float16)x0;
    lds[1][0][tid][36] = xh0;
    lds[1][0][tid][37] = (_Float16)(x0 - (float)xh0);
  }
  __syncthreads();

  // ---- Operand setup (A0/A1 shared by both wave kinds) ----
  f16x8 A0 = {}, A1 = {};
  float c1 = 0.f;   // A-wave cell state
  int ku = 0;
  if (isA) {
    const int u0 = wid * 4;
    ku = u0 + q;  // this lane's unit (C rows 4q+r = unit u0+q, gate r)
    const float sga = ((m & 3) == 2) ? -2.88539008f : -1.44269504f;
    const int ra = (m & 3) * H1 + (u0 + (m >> 2));
#pragma unroll
    for (int j = 0; j < 8; ++j)
      A0[j] = (_Float16)(sga * Whh1[ra * H1 + q * 8 + j]);  // k=q*8+j < 32
    if (q == 0) {
#pragma unroll
      for (int j = 0; j < 4; ++j)
        A1[j] = (_Float16)(sga * Whh1[ra * H1 + 32 + j]);  // tail k=32..35
      const _Float16 wih = (_Float16)(sga * Wih1[ra]);
      A1[4] = wih;  // * x_hi
      A1[5] = wih;  // * x_lo
      const float bb = sga * (bih1[ra] + bhh1[ra]);
      const _Float16 bh = (_Float16)bb;
      A1[6] = bh;                           // * 1.0
      A1[7] = (_Float16)(bb - (float)bh);   // * 1.0 (bias residual)
    }
  } else {
    // L2-MFMA wave: A row m = gate m for m<4 (pre-scaled), rows 4..15 zero.
    // Lane (q=0, m) then receives all 4 gate pre-acts for batch m in cc[0..3].
    if (m < 4) {
      const float s2 = (m == 2) ? -2.88539008f : -1.44269504f;
      const float* wr = Wih2 + m * H1;
#pragma unroll
      for (int j = 0; j < 8; ++j)
        A0[j] = (_Float16)(s2 * wr[q * 8 + j]);
      if (q == 0) {
#pragma unroll
        for (int j = 0; j < 4; ++j)
          A1[j] = (_Float16)(s2 * wr[32 + j]);  // tail k=32..35
        // A1[4],A1[5] stay 0 (x columns absent in layer 2)
        const float bb = s2 * (bih2[m] + bhh2[m]);
        const _Float16 bh = (_Float16)bb;
        A1[6] = bh;
        A1[7] = (_Float16)(bb - (float)bh);
      }
    }
  }

  // ---- Precomputed LDS read pointers (loop-invariant).
  // B1 broadcast trick: q!=0 lanes' B1 is structurally zero -> all point at ONE
  // shared zero 16B region (same-address -> LDS broadcast, ~free service).
  const _Float16* zr = &lds[0][1][0][40];  // never written, stays zero
  const int pl = isA ? 0 : 1;              // A reads raw, L2 reads relu
  const _Float16* b0p0 = &lds[0][pl][m][q * 8];
  const _Float16* b0p1 = &lds[1][pl][m][q * 8];
  const _Float16* b1p0 = (q == 0) ? &lds[0][pl][m][32] : zr;
  const _Float16* b1p1 = (q == 0) ? &lds[1][pl][m][32] : zr;

  // ---- L2 wave extras: per-gate recurrent weights, x-feeder state ----
  float whg4[4] = {0.f, 0.f, 0.f, 0.f};
  float c2S = 0.f, h2 = 0.f;
  float* outp = nullptr;
  const float* xc = nullptr;
  float4 qx = make_float4(0.f, 0.f, 0.f, 0.f);
  if (wid == 9) {
#pragma unroll
    for (int r = 0; r < 4; ++r)
      whg4[r] = ((r == 2) ? -2.88539008f : -1.44269504f) * Whh2[r];
    outp = out + (size_t)(g0 + m) * T_LEN;
    xc = x + (size_t)(g0 + m) * T_LEN;
    if (lane < 16) qx = *(const float4*)xc;  // x[0..3]
  }

  float4 ov = make_float4(0.f, 0.f, 0.f, 0.f);
  const f32x4 z4 = {0.f, 0.f, 0.f, 0.f};

  // Round i: A-waves compute h_i from buf[ib] (h_{i-1}, x_i) and write h_i /
  // relu(h_i) into buf[wb]; L2 wave feeds x_{i+1} into buf[wb] and computes
  // out[i-1] from buf[ib]'s relu plane. One raw barrier per round.
  // T5: A-waves (the round-critical chain) run their dependent section at
  // priority 1 so they win per-cycle issue arbitration on SIMDs shared with
  // the slack-laden L2 wave. No memory/numerics/sync change vs R8.
  auto step = [&](int i, int s, float xw) {
    const int ib = (s + 1) & 1;
    const int wb = s & 1;
    if (wid == 9 && lane < 16) {  // x_{i+1} feed (slack-side work)
      const _Float16 xh = (_Float16)xw;
      h16x2 xp = {xh, (_Float16)(xw - (float)xh)};
      *(h16x2*)&lds[wb][0][lane][36] = xp;
    }
    if (isA || i > 0) {
      if (isA) __builtin_amdgcn_s_setprio(1);
      const f16x8 B0 = *(const f16x8*)(ib ? b0p1 : b0p0);
      const f16x8 B1 = *(const f16x8*)(ib ? b1p1 : b1p0);
      const f32x4 cc1 = __builtin_amdgcn_mfma_f32_16x16x32_f16(A0, B0, z4, 0, 0, 0);
      const f32x4 cc2 = __builtin_amdgcn_mfma_f32_16x16x32_f16(A1, B1, z4, 0, 0, 0);
      if (isA) {
        const float h = lstm_unit(cc1[0] + cc2[0], cc1[1] + cc2[1],
                                  cc1[2] + cc2[2], cc1[3] + cc2[3], c1);
        const _Float16 hh = (_Float16)h;
        lds[wb][0][m][ku] = hh;
        lds[wb][1][m][ku] = (hh > (_Float16)0.f) ? hh : (_Float16)0.f;
        __builtin_amdgcn_s_setprio(0);
      } else {
        // lane (q=0, m): cc[r] = s2(r)*(W2_r . relu(h_{i-1}) + b2_r); add the
        // lane-local recurrent term and activate. q!=0 lanes compute bounded
        // garbage (zero A rows) that is never read or stored.
        float pre[4];
#pragma unroll
        for (int r = 0; r < 4; ++r)
          pre[r] = fmaf(whg4[r], h2, cc1[r] + cc2[r]);
        h2 = lstm_unit(pre[0], pre[1], pre[2], pre[3], c2S);  // = out[i-1]
        if (s == 1) ov.x = h2;
        else if (s == 2) ov.y = h2;
        else if (s == 3) ov.z = h2;
        else {
          ov.w = h2;
          if (lane < 16) *(float4*)(outp + (i - 4)) = ov;  // out[i-4..i-1]
        }
      }
    }
    step_sync();
  };

  for (int i0 = 0; i0 < T_LEN; i0 += 4) {
    float4 qn = qx;
    if (wid == 9 && lane < 16) {  // prefetch next x quad (clamped at tail)
      const int tn = (i0 + 4 < T_LEN) ? (i0 + 4) : (T_LEN - 4);
      qn = *(const float4*)(xc + tn);
    }
    step(i0 + 0, 0, qx.y);  // write x[i0+1]
    step(i0 + 1, 1, qx.z);  // write x[i0+2]
    step(i0 + 2, 2, qx.w);  // write x[i0+3]
    step(i0 + 3, 3, qn.x);  // write x[i0+4]
    qx = qn;
  }
  // Final round: A computes discarded h_2048; L2 emits out[2047] and stores
  // out[2044..2047].
  step(T_LEN, 0, qx.y);
}

}  // namespace

extern "C" void kernel_launch(void* const* d_in, const int* in_sizes, int n_in,
                              void* d_out, int out_size, void* d_ws, size_t ws_size,
                              hipStream_t stream) {
  const float* x    = (const float*)d_in[0];
  const float* Wih1 = (const float*)d_in[1];
  const float* Whh1 = (const float*)d_in[2];
  const float* bih1 = (const float*)d_in[3];
  const float* bhh1 = (const float*)d_in[4];
  const float* Wih2 = (const float*)d_in[5];
  const float* Whh2 = (const float*)d_in[6];
  const float* bih2 = (const float*)d_in[7];
  const float* bhh2 = (const float*)d_in[8];
  float* out = (float*)d_out;

  dim3 grid(B_TOT / NB);  // 128 blocks x 16 batches
  dim3 block(BLOCK);      // 9 A-waves + 1 L2-MFMA/x-feeder wave
  hipLaunchKernelGGL(lstm2_kernel, grid, block, 0, stream,
                     x, Wih1, Whh1, bih1, bhh1, Wih2, Whh2, bih2, bhh2, out);
}